// Round 4
// baseline (744.343 us; speedup 1.0000x reference)
//
#include <hip/hip_runtime.h>
#include <stdint.h>
#include <stddef.h>

typedef _Float16 half_t;
typedef _Float16 half8 __attribute__((ext_vector_type(8)));
typedef float float4v __attribute__((ext_vector_type(4)));

#define D_DIM 1792
#define B_DIM 8192
#define LD D_DIM

// ---------------------------------------------------------------------------
// Async global->LDS staging (big GEMMs only). slot = chunk ^ ((row>>1)&3):
// conflict-free (verified R2: SQ_LDS_BANK_CONFLICT 6.4e6 -> 0).
// ---------------------------------------------------------------------------
__device__ __forceinline__ void stage_rows(const half_t* __restrict__ src, int row0, int ld,
                                           int k0, half_t* dst, int nchunks, int tid) {
  for (int base = 0; base < nchunks; base += 256) {
    int ch  = base + tid;
    int row = ch >> 2, kc = ch & 3;
    int swz = kc ^ ((row >> 1) & 3);
    const half_t* g = src + (size_t)(row0 + row) * ld + k0 + swz * 8;
    half_t* l = dst + (size_t)(base + (tid & 192)) * 8;   // wave-uniform base; HW adds lane*16B
    __builtin_amdgcn_global_load_lds(
        (const __attribute__((address_space(1))) uint32_t*)(const void*)g,
        (__attribute__((address_space(3))) uint32_t*)(void*)l, 16, 0, 0);
  }
}

__device__ __forceinline__ half8 frag32(const half_t* lds, int row, int chunk) {
  int slot = chunk ^ ((row >> 1) & 3);
  return *(const half8*)(lds + row * 32 + slot * 8);
}
// 256-wide LDS rows (Us in the solve): row*256 stride, low-4 XOR swizzle.
__device__ __forceinline__ half8 frag256(const half_t* lds, int row, int chunk) {
  int slot = chunk ^ (row & 15);
  return *(const half8*)(lds + row * 256 + slot * 8);
}

// ---------------------------------------------------------------------------
// 1. Row-normalize U -> Vh (fp16). One block per row.
// ---------------------------------------------------------------------------
__global__ __launch_bounds__(256) void normalize_rows(const float* __restrict__ U,
                                                      half_t* __restrict__ Vh) {
  int r = blockIdx.x, t = threadIdx.x;
  float v[7];
  float s = 0.f;
#pragma unroll
  for (int i = 0; i < 7; ++i) {
    v[i] = U[(size_t)r * D_DIM + t + i * 256];
    s += v[i] * v[i];
  }
#pragma unroll
  for (int m = 32; m; m >>= 1) s += __shfl_xor(s, m);
  __shared__ float red[4];
  __shared__ float tot;
  if ((t & 63) == 0) red[t >> 6] = s;
  __syncthreads();
  if (t == 0) tot = 1.0f / sqrtf(red[0] + red[1] + red[2] + red[3]);
  __syncthreads();
  float rn = tot;
#pragma unroll
  for (int i = 0; i < 7; ++i)
    Vh[(size_t)r * D_DIM + t + i * 256] = (half_t)(v[i] * rn);
}

// ---------------------------------------------------------------------------
// 2. Transpose X (fp32, D x B) -> XT (fp16, B x D). 64x64 LDS tiles.
// ---------------------------------------------------------------------------
__global__ __launch_bounds__(256) void transpose_x(const float* __restrict__ X,
                                                   half_t* __restrict__ XT) {
  __shared__ half_t t[64][68];
  int r0 = blockIdx.x * 64, c0 = blockIdx.y * 64;
  int tid = threadIdx.x;
#pragma unroll
  for (int i = 0; i < 16; ++i) {
    int f = tid + i * 256;
    int rr = f >> 6, cc = f & 63;
    t[rr][cc] = (half_t)X[(size_t)(r0 + rr) * B_DIM + c0 + cc];
  }
  __syncthreads();
#pragma unroll
  for (int i = 0; i < 16; ++i) {
    int f = tid + i * 256;
    int cc = f >> 6, rr = f & 63;
    XT[(size_t)(c0 + cc) * D_DIM + r0 + rr] = t[rr][cc];
  }
}

// ---------------------------------------------------------------------------
// 2b. Transpose Vh (fp16, D x D) -> VhT.
// ---------------------------------------------------------------------------
__global__ __launch_bounds__(256) void transpose_h(const half_t* __restrict__ Vh,
                                                   half_t* __restrict__ VhT) {
  __shared__ half_t t[64][68];
  int r0 = blockIdx.x * 64, c0 = blockIdx.y * 64;
  int tid = threadIdx.x;
#pragma unroll
  for (int i = 0; i < 16; ++i) {
    int f = tid + i * 256;
    int rr = f >> 6, cc = f & 63;
    t[rr][cc] = Vh[(size_t)(r0 + rr) * D_DIM + c0 + cc];
  }
  __syncthreads();
#pragma unroll
  for (int i = 0; i < 16; ++i) {
    int f = tid + i * 256;
    int cc = f >> 6, rr = f & 63;
    VhT[(size_t)(c0 + cc) * D_DIM + r0 + rr] = t[rr][cc];
  }
}

// ---------------------------------------------------------------------------
// 3. Big NT MFMA GEMM: acc[m][n] = sum_k A[m][k]*B[n][k], 128x128 tile, BK=32.
//    MODE 0 (gram->T16): triangular block skip; Ch = (c<r) ? 2*acc : 0  (fp16)
//    MODE 1 (Pf build):  Ch = (r==c ? 1 : 0) - acc                      (fp16)
//    MODE 2 (final):     Cf = acc                                       (fp32)
// ---------------------------------------------------------------------------
template <int MODE>
__global__ __launch_bounds__(256) void gemm_nt(const half_t* __restrict__ A,
                                               const half_t* __restrict__ B,
                                               float* __restrict__ Cf, half_t* __restrict__ Ch,
                                               int K, int lda, int ldb, int ldc) {
  int m0 = blockIdx.y * 128, n0 = blockIdx.x * 128;
  if constexpr (MODE == 0) { if (n0 > m0) return; }   // gram: lower+diag blocks only
  __shared__ half_t sA[128 * 32];
  __shared__ half_t sB[128 * 32];
  int tid = threadIdx.x, lane = tid & 63, wave = tid >> 6;
  int ln15 = lane & 15, quad = lane >> 4;
  int wr = (wave & 1) * 64, wc = (wave >> 1) * 64;
  float4v acc[4][4] = {};
  for (int kb = 0; kb < K / 32; ++kb) {
    stage_rows(A, m0, lda, kb * 32, sA, 512, tid);
    stage_rows(B, n0, ldb, kb * 32, sB, 512, tid);
    __syncthreads();
    half8 af[4], bf[4];
#pragma unroll
    for (int i = 0; i < 4; ++i) af[i] = frag32(sA, wr + i * 16 + ln15, quad);
#pragma unroll
    for (int j = 0; j < 4; ++j) bf[j] = frag32(sB, wc + j * 16 + ln15, quad);
#pragma unroll
    for (int i = 0; i < 4; ++i)
#pragma unroll
      for (int j = 0; j < 4; ++j)
        acc[i][j] = __builtin_amdgcn_mfma_f32_16x16x32_f16(af[i], bf[j], acc[i][j], 0, 0, 0);
    __syncthreads();
  }
#pragma unroll
  for (int i = 0; i < 4; ++i)
#pragma unroll
    for (int j = 0; j < 4; ++j)
#pragma unroll
      for (int rg = 0; rg < 4; ++rg) {
        int row = m0 + wr + i * 16 + quad * 4 + rg;
        int col = n0 + wc + j * 16 + ln15;
        size_t idx = (size_t)row * ldc + col;
        float v = acc[i][j][rg];
        if constexpr (MODE == 0) Ch[idx] = (col < row) ? (half_t)(2.0f * v) : (half_t)0.0f;
        else if constexpr (MODE == 1) Ch[idx] = (half_t)(((row == col) ? 1.0f : 0.0f) - v);
        else Cf[idx] = v;
      }
}

// ---------------------------------------------------------------------------
// 4. Invert 7 diagonal 256x256 unit-lower-triangular blocks of T.
//    Packed strict-lower triangle in LDS (63.75 KB fp16). One wave per column;
//    forward substitution, x kept in registers (butterfly gives all lanes the
//    sum, so predicated register updates need no LDS round-trip).
//    Grid 7*32 WGs of 512 threads (8 columns/WG).  -> Dinv (fp16, 7x256x256)
// ---------------------------------------------------------------------------
__global__ __launch_bounds__(512) void diag_inv(const half_t* __restrict__ T16,
                                                half_t* __restrict__ Dinv) {
  __shared__ half_t Ls[32640];          // row r at r*(r-1)/2, length r (strict lower)
  int b = blockIdx.x >> 5, cg = blockIdx.x & 31;
  int tid = threadIdx.x, wave = tid >> 6, ln = tid & 63;
  int c = cg * 8 + wave;                // this wave's column (0..255)
  const half_t* Tb = T16 + (size_t)(b * 256) * LD + b * 256;
  for (int idx = tid; idx < 32640; idx += 512) {
    int r = (int)((sqrtf(8.f * (float)idx + 1.f) + 1.f) * 0.5f);
    while (r * (r - 1) / 2 > idx) --r;
    while ((r + 1) * r / 2 <= idx) ++r;
    int j = idx - r * (r - 1) / 2;
    Ls[idx] = Tb[(size_t)r * LD + j];
  }
  __syncthreads();
  float x0 = (ln == 0) ? 1.f : 0.f, x1 = 0.f, x2 = 0.f, x3 = 0.f;
  int j0 = c + ln, j1 = j0 + 64, j2 = j0 + 128, j3 = j0 + 192;
  for (int r = c + 1; r < 256; ++r) {
    int base = (r * (r - 1)) >> 1;
    float ta = 0.f;
    if (j0 < r) ta += (float)Ls[base + j0] * x0;
    if (j1 < r) ta += (float)Ls[base + j1] * x1;
    if (j2 < r) ta += (float)Ls[base + j2] * x2;
    if (j3 < r) ta += (float)Ls[base + j3] * x3;
#pragma unroll
    for (int m = 32; m; m >>= 1) ta += __shfl_xor(ta, m);
    float xr = -ta;
    if (j0 == r) x0 = xr;
    if (j1 == r) x1 = xr;
    if (j2 == r) x2 = xr;
    if (j3 == r) x3 = xr;
  }
  half_t* Db = Dinv + (size_t)b * 65536;
  if (j0 < 256) Db[(size_t)j0 * 256 + c] = (half_t)x0;
  if (j1 < 256) Db[(size_t)j1 * 256 + c] = (half_t)x1;
  if (j2 < 256) Db[(size_t)j2 * 256 + c] = (half_t)x2;
  if (j3 < 256) Db[(size_t)j3 * 256 + c] = (half_t)x3;
  for (int j = ln; j < c; j += 64) Db[(size_t)j * 256 + c] = (half_t)0;  // upper zeros
}

// ---------------------------------------------------------------------------
// 5. Fused blocked forward substitution — one launch, 7 panels of 256.
//    VGPR-pipelined staging: plain global loads for tile k+1 issue during
//    compute of tile k; ds_write at step top. No global_load_lds -> no
//    vmcnt(0)-drain-before-barrier on the critical path (R3's 1300 cyc/step).
//    56 blocks x 32 m-rows. Cross-panel WtT write->read ordered by the
//    top-of-panel __syncthreads (vmcnt0 drain) + same-CU L1 (R3-proven).
//    Per panel ib (pr0 = ib*256):
//      Ut[m][s]  = 2*Vn[pr0+s][m] - sum_{k<pr0} WtT[m][k]*T16[pr0+s][k]
//      WtT[m][pr0+r] = sum_s Ut[m][s]*Dinv[ib][r][s]
// ---------------------------------------------------------------------------
__global__ __launch_bounds__(256) void fused_solve(const half_t* __restrict__ T16,
                                                   const half_t* __restrict__ Vh,
                                                   const half_t* __restrict__ Dinv,
                                                   half_t* __restrict__ WtT) {
  __shared__ half_t sA[32 * 32];     //  2 KB WtT tile
  __shared__ half_t sB[256 * 32];    // 16 KB T16 / Dinv tile
  __shared__ half_t Us[32 * 256];    // 16 KB Ut in A-operand layout (swizzled)
  int tid = threadIdx.x, lane = tid & 63, wave = tid >> 6;
  int ln15 = lane & 15, quad = lane >> 4;
  int m0 = blockIdx.x * 32;
  int wc = wave * 64;                // wave's s / r quarter
  int brow = tid >> 2, bkc = tid & 3;       // B staging: rows brow + i*64
  int arow = tid >> 2, akc = tid & 3;       // A staging (threads < 128): rows 0..31

  for (int ib = 0; ib < 7; ++ib) {
    __syncthreads();   // drain prev panel's WtT stores before re-reading them
    int pr0 = ib * 256;
    float4v acc[2][4] = {};
    int Ksteps = ib * 8;
    uint4 rA{}; uint4 rB[4];
    if (Ksteps > 0) {
      if (tid < 128) rA = *(const uint4*)(WtT + (size_t)(m0 + arow) * LD + akc * 8);
#pragma unroll
      for (int i = 0; i < 4; ++i)
        rB[i] = *(const uint4*)(T16 + (size_t)(pr0 + i * 64 + brow) * LD + bkc * 8);
    }
    for (int kb = 0; kb < Ksteps; ++kb) {
      __syncthreads();   // previous tile fully consumed
      if (tid < 128) *(uint4*)(sA + arow * 32 + (akc ^ ((arow >> 1) & 3)) * 8) = rA;
#pragma unroll
      for (int i = 0; i < 4; ++i) {
        int row = i * 64 + brow;
        *(uint4*)(sB + row * 32 + (bkc ^ ((row >> 1) & 3)) * 8) = rB[i];
      }
      __syncthreads();
      if (kb + 1 < Ksteps) {   // prefetch next tile: in flight during compute
        int k0 = (kb + 1) * 32;
        if (tid < 128) rA = *(const uint4*)(WtT + (size_t)(m0 + arow) * LD + k0 + akc * 8);
#pragma unroll
        for (int i = 0; i < 4; ++i)
          rB[i] = *(const uint4*)(T16 + (size_t)(pr0 + i * 64 + brow) * LD + k0 + bkc * 8);
      }
      half8 af[2], bf[4];
#pragma unroll
      for (int i = 0; i < 2; ++i) af[i] = frag32(sA, i * 16 + ln15, quad);
#pragma unroll
      for (int j = 0; j < 4; ++j) bf[j] = frag32(sB, wc + j * 16 + ln15, quad);
#pragma unroll
      for (int i = 0; i < 2; ++i)
#pragma unroll
        for (int j = 0; j < 4; ++j)
          acc[i][j] = __builtin_amdgcn_mfma_f32_16x16x32_f16(af[i], bf[j], acc[i][j], 0, 0, 0);
    }
    // prefetch Dinv tile 0 (overlaps phase-2 latency)
#pragma unroll
    for (int i = 0; i < 4; ++i)
      rB[i] = *(const uint4*)(Dinv + (size_t)ib * 65536 + (size_t)(i * 64 + brow) * 256 + bkc * 8);
    // phase 2: Us = 2*VnT - acc  (A-operand layout, frag256 swizzle)
#pragma unroll
    for (int i = 0; i < 2; ++i)
#pragma unroll
      for (int j = 0; j < 4; ++j)
#pragma unroll
        for (int rg = 0; rg < 4; ++rg) {
          int rl = i * 16 + quad * 4 + rg;
          int cl = wc + j * 16 + ln15;
          float vn = (float)Vh[(size_t)(pr0 + cl) * LD + m0 + rl];
          float u = 2.f * vn - acc[i][j][rg];
          Us[rl * 256 + (((cl >> 3) ^ (rl & 15)) << 3) + (cl & 7)] = (half_t)u;
        }
    // phase 3: apply diag inverse, K=256 over s, same pipelined staging
    float4v a2[2][4] = {};
    for (int kb2 = 0; kb2 < 8; ++kb2) {
      __syncthreads();   // kb2=0: Us visible & sB free; else previous tile consumed
#pragma unroll
      for (int i = 0; i < 4; ++i) {
        int row = i * 64 + brow;
        *(uint4*)(sB + row * 32 + (bkc ^ ((row >> 1) & 3)) * 8) = rB[i];
      }
      __syncthreads();
      if (kb2 + 1 < 8) {
        int k0 = (kb2 + 1) * 32;
#pragma unroll
        for (int i = 0; i < 4; ++i)
          rB[i] = *(const uint4*)(Dinv + (size_t)ib * 65536 + (size_t)(i * 64 + brow) * 256 + k0 + bkc * 8);
      }
      half8 af[2], bf[4];
#pragma unroll
      for (int i = 0; i < 2; ++i) af[i] = frag256(Us, i * 16 + ln15, kb2 * 4 + quad);
#pragma unroll
      for (int j = 0; j < 4; ++j) bf[j] = frag32(sB, wc + j * 16 + ln15, quad);
#pragma unroll
      for (int i = 0; i < 2; ++i)
#pragma unroll
        for (int j = 0; j < 4; ++j)
          a2[i][j] = __builtin_amdgcn_mfma_f32_16x16x32_f16(af[i], bf[j], a2[i][j], 0, 0, 0);
    }
    // store panel columns
#pragma unroll
    for (int i = 0; i < 2; ++i)
#pragma unroll
      for (int j = 0; j < 4; ++j)
#pragma unroll
        for (int rg = 0; rg < 4; ++rg) {
          int rl = i * 16 + quad * 4 + rg;
          int cl = wc + j * 16 + ln15;
          WtT[(size_t)(m0 + rl) * LD + pr0 + cl] = (half_t)a2[i][j][rg];
        }
  }
}

// ---------------------------------------------------------------------------
extern "C" void kernel_launch(void* const* d_in, const int* in_sizes, int n_in,
                              void* d_out, int out_size, void* d_ws, size_t ws_size,
                              hipStream_t stream) {
  (void)in_sizes; (void)n_in; (void)out_size; (void)ws_size;
  const float* X = (const float*)d_in[0];   // (1792, 8192) fp32
  const float* U = (const float*)d_in[1];   // (1792, 1792) fp32
  float* out = (float*)d_out;               // (1792, 8192) fp32

  char* ws = (char*)d_ws;
  half_t* XT   = (half_t*)(ws);                    // 29,360,128 B
  half_t* Vh   = (half_t*)(ws + 29360128);         //  6,422,528 B
  half_t* VhT  = (half_t*)(ws + 35782656);         //  6,422,528 B
  half_t* T16  = (half_t*)(ws + 42205184);         //  6,422,528 B
  half_t* WtT  = (half_t*)(ws + 48627712);         //  6,422,528 B
  half_t* Dinv = (half_t*)(ws + 55050240);         //    917,504 B (dead after solve)
  half_t* Pf   = (half_t*)(ws + 55050240);         //  6,422,528 B (aliases Dinv)
  // total footprint: 61,472,768 B

  normalize_rows<<<dim3(D_DIM), dim3(256), 0, stream>>>(U, Vh);
  transpose_x<<<dim3(D_DIM / 64, B_DIM / 64), dim3(256), 0, stream>>>(X, XT);
  // T16 = 2*strict_tril(Vn Vn^T) (zeros on/above diagonal)
  gemm_nt<0><<<dim3(14, 14), dim3(256), 0, stream>>>(Vh, Vh, nullptr, T16,
                                                     D_DIM, D_DIM, D_DIM, D_DIM);
  transpose_h<<<dim3(28, 28), dim3(256), 0, stream>>>(Vh, VhT);
  diag_inv<<<dim3(224), dim3(512), 0, stream>>>(T16, Dinv);
  // one-launch blocked forward substitution: WtT = (T^{-1} 2Vn)^T
  fused_solve<<<dim3(56), dim3(256), 0, stream>>>(T16, Vh, Dinv, WtT);
  // Pf = I - Wt^T Vn
  gemm_nt<1><<<dim3(14, 14), dim3(256), 0, stream>>>(WtT, VhT, nullptr, Pf,
                                                     D_DIM, D_DIM, D_DIM, D_DIM);
  // out = Pf X :  out[i][j] = sum_k Pf[i][k]*XT[j][k]
  gemm_nt<2><<<dim3(64, 14), dim3(256), 0, stream>>>(Pf, XT, out, nullptr,
                                                     D_DIM, D_DIM, D_DIM, B_DIM);
}